// Round 1
// baseline (2385.841 us; speedup 1.0000x reference)
//
#include <hip/hip_runtime.h>
#include <stdint.h>

// ---------------------------------------------------------------------------
// GAFD_ABCD pipeline on MI355X.
// B=16, Ct=1024, Cs=512, H=W=64, anchors N=256, proj P=256.
// conv1(3x3,1024->512)+relu fused with conv2(1x1,512->1) as bf16 MFMA
// implicit GEMM (9 shifted taps over a zero-padded bf16 NHWC copy).
// ---------------------------------------------------------------------------

typedef float f32x4 __attribute__((ext_vector_type(4)));
typedef short s16x8 __attribute__((ext_vector_type(8)));

__device__ __forceinline__ unsigned short f2bf(float f) {
  unsigned u = __float_as_uint(f);
  u += 0x7fffu + ((u >> 16) & 1u);   // RNE
  return (unsigned short)(u >> 16);
}

__device__ __forceinline__ void gld16(const void* g, void* l) {
  __builtin_amdgcn_global_load_lds(
      (const __attribute__((address_space(1))) void*)g,
      (__attribute__((address_space(3))) void*)l, 16, 0, 0);
}

__device__ __forceinline__ float block_sum(float v, float* l4) {
  for (int m = 32; m; m >>= 1) v += __shfl_xor(v, m, 64);
  int wid = threadIdx.x >> 6;
  if ((threadIdx.x & 63) == 0) l4[wid] = v;
  __syncthreads();
  float r = l4[0] + l4[1] + l4[2] + l4[3];
  __syncthreads();
  return r;
}

// --------------------------- K0: pad-transpose -----------------------------
// teacher [16,1024,64,64] f32 -> tpad [16][66][66][1024] bf16 (interior only;
// borders zeroed by memset before this kernel).
__global__ void k_pad_transpose(const float* __restrict__ teacher,
                                unsigned short* __restrict__ tpad) {
  __shared__ __align__(16) unsigned short lds[64 * 65];
  int bid = blockIdx.x;
  int cb = bid & 15, y = (bid >> 4) & 63, b = bid >> 10;
  int t = threadIdx.x;
#pragma unroll
  for (int it = 0; it < 16; ++it) {
    int idx = it * 256 + t;
    int cl = idx >> 6, x = idx & 63;
    float v = teacher[(size_t)(b * 1024 + cb * 64 + cl) * 4096 + y * 64 + x];
    lds[cl * 65 + x] = f2bf(v);
  }
  __syncthreads();
  size_t obase = ((size_t)(b * 66 + y + 1) * 66 + 1) * 1024 + cb * 64;
#pragma unroll
  for (int it = 0; it < 16; ++it) {
    int x = it * 4 + (t >> 6);
    int cl = t & 63;
    tpad[obase + (size_t)x * 1024 + cl] = lds[cl * 65 + x];
  }
}

// --------------------------- K0b: weight prep ------------------------------
// conv1_w [co=512][ci=1024][ky][kx] -> wt[tap][kb][co 512][kc 64] bf16
__global__ void k_wprep(const float* __restrict__ w1,
                        unsigned short* __restrict__ wt) {
  int e = blockIdx.x * 256 + threadIdx.x;  // < 9*16*512*64 = 4718592
  int kc = e & 63;
  int co = (e >> 6) & 511;
  int kb = (e >> 15) & 15;
  int tap = e >> 19;
  if (tap >= 9) return;
  float v = w1[(size_t)(co * 1024 + kb * 64 + kc) * 9 + tap];
  wt[e] = f2bf(v);
}

// --------------------------- K1: conv GEMM ---------------------------------
// M = 65536 pixels, N = 512 co, K = 9*1024. 128x128 tiles, BK=64.
// Epilogue: relu(acc+b1)*w2 summed over co -> atomicAdd heat[pixel].
__global__ __launch_bounds__(256) void k_conv(
    const unsigned short* __restrict__ tpad, const unsigned short* __restrict__ wt,
    const float* __restrict__ b1, const float* __restrict__ w2,
    float* __restrict__ heat) {
  __shared__ __align__(16) unsigned short As[128 * 64];
  __shared__ __align__(16) unsigned short Bs[128 * 64];
  int bid = blockIdx.x;
  int nt = bid & 3, mt = bid >> 2;
  int p0 = mt * 128;
  int b = p0 >> 12, y0 = (p0 >> 6) & 63;
  int co0 = nt * 128;
  int t = threadIdx.x, wid = t >> 6, lane = t & 63;
  int wm = wid & 1, wn = wid >> 1;
  int quad = lane >> 4, l15 = lane & 15;

  f32x4 acc[4][4];
  const f32x4 fz = {0.f, 0.f, 0.f, 0.f};
#pragma unroll
  for (int i = 0; i < 4; ++i)
#pragma unroll
    for (int j = 0; j < 4; ++j) acc[i][j] = fz;

  int xj[4], yrj[4];
#pragma unroll
  for (int jj = 0; jj < 4; ++jj) {
    int m = (wid * 4 + jj) * 8 + (lane >> 3);
    xj[jj] = m & 63;
    yrj[jj] = m >> 6;
  }
  int kcol = (lane & 7) * 8;
  const unsigned short* wt_nt = wt + (size_t)co0 * 64;

  for (int tap = 0; tap < 9; ++tap) {
    int ky = tap / 3, kx = tap - ky * 3;
    size_t abase[4];
#pragma unroll
    for (int jj = 0; jj < 4; ++jj) {
      int row = y0 + yrj[jj] + ky;
      int col = xj[jj] + kx;
      abase[jj] = ((size_t)(b * 66 + row) * 66 + col) * 1024 + kcol;
    }
    size_t bbase = (size_t)tap * 16 * 32768;
    for (int kb = 0; kb < 16; ++kb) {
#pragma unroll
      for (int jj = 0; jj < 4; ++jj) {
        gld16(tpad + abase[jj] + kb * 64, (char*)As + (wid * 4 + jj) * 1024);
        gld16(wt_nt + bbase + (size_t)kb * 32768 + (wid * 4 + jj) * 512 + lane * 8,
              (char*)Bs + (wid * 4 + jj) * 1024);
      }
      __syncthreads();
#pragma unroll
      for (int s = 0; s < 2; ++s) {
        s16x8 af[4], bf[4];
#pragma unroll
        for (int i = 0; i < 4; ++i) {
          af[i] = *(const s16x8*)(const void*)(As + (wm * 64 + i * 16 + l15) * 64 + s * 32 + quad * 8);
          bf[i] = *(const s16x8*)(const void*)(Bs + (wn * 64 + i * 16 + l15) * 64 + s * 32 + quad * 8);
        }
#pragma unroll
        for (int i = 0; i < 4; ++i)
#pragma unroll
          for (int j = 0; j < 4; ++j)
            acc[i][j] = __builtin_amdgcn_mfma_f32_16x16x32_bf16(af[i], bf[j], acc[i][j], 0, 0, 0);
      }
      __syncthreads();
    }
  }

  float w2v[4], b1v[4];
#pragma unroll
  for (int j = 0; j < 4; ++j) {
    int co = co0 + wn * 64 + j * 16 + l15;
    w2v[j] = w2[co];
    b1v[j] = b1[co];
  }
#pragma unroll
  for (int i = 0; i < 4; ++i) {
#pragma unroll
    for (int r = 0; r < 4; ++r) {
      float part = 0.f;
#pragma unroll
      for (int j = 0; j < 4; ++j) {
        float v = acc[i][j][r] + b1v[j];
        v = fmaxf(v, 0.f);
        part += v * w2v[j];
      }
#pragma unroll
      for (int msk = 1; msk < 16; msk <<= 1) part += __shfl_xor(part, msk, 64);
      if (l15 == 0) {
        int m = wm * 64 + i * 16 + quad * 4 + r;
        atomicAdd(&heat[p0 + m], part);
      }
    }
  }
}

// --------------------------- threefry (JAX partitionable) ------------------
__device__ __forceinline__ unsigned rotl32(unsigned x, int d) {
  return (x << d) | (x >> (32 - d));
}
__device__ unsigned threefry_bits(unsigned lo) {
  const unsigned k0 = 0u, k1 = 42u;
  const unsigned k2 = 0x1BD11BDAu ^ k0 ^ k1;
  unsigned x0 = 0u + k0, x1 = lo + k1;
#define TF_R4(a, bq, c, d)                                \
  x0 += x1; x1 = rotl32(x1, a); x1 ^= x0;                 \
  x0 += x1; x1 = rotl32(x1, bq); x1 ^= x0;                \
  x0 += x1; x1 = rotl32(x1, c); x1 ^= x0;                 \
  x0 += x1; x1 = rotl32(x1, d); x1 ^= x0;
  TF_R4(13, 15, 26, 6)  x0 += k1; x1 += k2 + 1u;
  TF_R4(17, 29, 16, 24) x0 += k2; x1 += k0 + 2u;
  TF_R4(13, 15, 26, 6)  x0 += k0; x1 += k1 + 3u;
  TF_R4(17, 29, 16, 24) x0 += k1; x1 += k2 + 4u;
  TF_R4(13, 15, 26, 6)  x0 += k2; x1 += k0 + 5u;
#undef TF_R4
  return x0 ^ x1;  // partitionable 32-bit combine
}

// --------------------------- K2: softplus / prob / scores ------------------
__global__ void k_heat2score(const float* __restrict__ heat, const float* __restrict__ b2p,
                             float* __restrict__ out_hm, float* __restrict__ hm,
                             float* __restrict__ scores) {
  __shared__ float l4[4];
  int b = blockIdx.x, t = threadIdx.x;
  float b2 = b2p[0];
  float hv[16];
  float lsum = 0.f;
#pragma unroll
  for (int j = 0; j < 16; ++j) {
    int e = j * 256 + t;
    float x = heat[b * 4096 + e] + b2;
    float sp = fmaxf(x, 0.f) + log1pf(expf(-fabsf(x)));
    hv[j] = sp;
    lsum += sp;
  }
  float S = block_sum(lsum, l4);
  float denom = S + 1e-6f;
#pragma unroll
  for (int j = 0; j < 16; ++j) {
    int e = j * 256 + t;
    float sp = hv[j];
    out_hm[b * 4096 + e] = sp;
    hm[b * 4096 + e] = sp;
    float lp = logf(sp / denom + 1e-12f);
    unsigned bits = threefry_bits((unsigned)(b * 4096 + e));
    float u01 = __uint_as_float((bits >> 9) | 0x3f800000u) - 1.0f;
    float u = fmaxf(1e-8f, u01 * (1.0f - 1e-8f) + 1e-8f);
    float gum = -logf(-logf(u));
    scores[b * 4096 + e] = lp + gum;
  }
}

// --------------------------- K3: top-256 per batch row ---------------------
__global__ void k_topk(const float* __restrict__ scores, int* __restrict__ idx_sel) {
  __shared__ float sc[4096];
  __shared__ unsigned long long red[4];
  int b = blockIdx.x, t = threadIdx.x;
  for (int j = 0; j < 16; ++j) sc[j * 256 + t] = scores[b * 4096 + j * 256 + t];
  __syncthreads();
  for (int it = 0; it < 256; ++it) {
    unsigned long long best = 0ull;
#pragma unroll
    for (int j = 0; j < 16; ++j) {
      int e = j * 256 + t;
      unsigned u = __float_as_uint(sc[e]);
      u = (u & 0x80000000u) ? ~u : (u | 0x80000000u);
      unsigned long long pk = ((unsigned long long)u << 32) | (unsigned)e;
      best = pk > best ? pk : best;
    }
    for (int m = 32; m; m >>= 1) {
      unsigned long long o = __shfl_xor(best, m, 64);
      best = o > best ? o : best;
    }
    if ((t & 63) == 0) red[t >> 6] = best;
    __syncthreads();
    if (t == 0) {
      unsigned long long w = red[0];
      for (int i = 1; i < 4; ++i) w = red[i] > w ? red[i] : w;
      int wi = (int)(w & 0xffffffffu);
      idx_sel[b * 256 + it] = wi;
      sc[wi] = -1e38f;
    }
    __syncthreads();
  }
}

// --------------------------- K4: bilinear gather (exact 0.25 taps) ---------
__global__ void k_gather(const float* __restrict__ feat, int C,
                         const int* __restrict__ idx_sel, float* __restrict__ out) {
  int bn = blockIdx.x;
  int b = bn >> 8;
  int idx = idx_sel[bn];
  int px = idx & 63, py = idx >> 6;
  const float* fb = feat + (size_t)b * C * 4096;
  for (int c = threadIdx.x; c < C; c += 256) {
    const float* pc = fb + (size_t)c * 4096;
    float v = 0.f;
    if (py > 0) {
      if (px > 0) v += pc[(py - 1) * 64 + px - 1];
      v += pc[(py - 1) * 64 + px];
    }
    if (px > 0) v += pc[py * 64 + px - 1];
    v += pc[py * 64 + px];
    out[(size_t)bn * C + c] = 0.25f * v;
  }
}

// --------------------------- K5: projection + LN + l2norm ------------------
// 8 rows/block, thread = output column p (256 threads).
__global__ void k_proj_ln(const float* __restrict__ src, int K,
                          const float* __restrict__ w, const float* __restrict__ bias,
                          const float* __restrict__ g, const float* __restrict__ beta,
                          float* __restrict__ outf, unsigned short* __restrict__ outb) {
  __shared__ float l4[4];
  int t = threadIdx.x;
  int n0 = blockIdx.x * 8;
  float acc[8];
#pragma unroll
  for (int r = 0; r < 8; ++r) acc[r] = 0.f;
  for (int k = 0; k < K; ++k) {
    float wv = w[k * 256 + t];
#pragma unroll
    for (int r = 0; r < 8; ++r) acc[r] += src[(size_t)(n0 + r) * K + k] * wv;
  }
  float bv = bias[t], gv = g[t], btv = beta[t];
  for (int r = 0; r < 8; ++r) {
    float x = acc[r] + bv;
    float s1 = block_sum(x, l4);
    float mu = s1 * (1.f / 256.f);
    float d = x - mu;
    float s2 = block_sum(d * d, l4);
    float rstd = rsqrtf(s2 * (1.f / 256.f) + 1e-5f);
    float xn = d * rstd * gv + btv;
    float ss = block_sum(xn * xn, l4);
    float nrm = sqrtf(ss);
    float o = xn / fmaxf(nrm, 1e-12f);
    size_t oi = (size_t)(n0 + r) * 256 + t;
    outf[oi] = o;
    if (outb) outb[oi] = f2bf(o);
  }
}

// --------------------------- K6: saliency / bd / pos -----------------------
__global__ void k_sal_pos(const float* __restrict__ hm, const int* __restrict__ idx_sel,
                          const float* __restrict__ ftn, const float* __restrict__ fsn,
                          int* __restrict__ bd, float* __restrict__ pos,
                          int* __restrict__ cnt, int* __restrict__ nbc) {
  __shared__ float l4[4];
  int b = blockIdx.x, t = threadIdx.x;
  int idx = idx_sel[b * 256 + t];
  int px = idx & 63, py = idx >> 6;
  const float* hb = hm + b * 4096;
  float v = 0.f;
  if (py > 0) {
    if (px > 0) v += hb[(py - 1) * 64 + px - 1];
    v += hb[(py - 1) * 64 + px];
  }
  if (px > 0) v += hb[py * 64 + px - 1];
  v += hb[py * 64 + px];
  float sal = 0.25f * v;
  float mx = sal;
  for (int m = 32; m; m >>= 1) mx = fmaxf(mx, __shfl_xor(mx, m, 64));
  if ((t & 63) == 0) l4[t >> 6] = mx;
  __syncthreads();
  mx = fmaxf(fmaxf(l4[0], l4[1]), fmaxf(l4[2], l4[3]));
  __syncthreads();
  int bdv = sal > 0.6f * mx ? 1 : 0;
  bd[b * 256 + t] = bdv;
  float c = block_sum((float)bdv, l4);
  if (t == 0) {
    cnt[b] = (int)c;
    nbc[b] = 256 - (int)c;
  }
  const float* fr = fsn + (size_t)(b * 256 + t) * 256;
  const float* tr = ftn + (size_t)(b * 256 + t) * 256;
  float s = 0.f;
  for (int cc = 0; cc < 256; ++cc) s += fr[cc] * tr[cc];
  pos[b * 256 + t] = s / 0.1f;
}

// --------------------------- K7: neg matrix + masked LSE -------------------
// Per (b, 64-row chunk): S = fs fs^T / TAU via bf16 MFMA, online logsumexp
// over columns with bd columns treated as exactly -1e30 (reference NEG_INF).
__global__ __launch_bounds__(256) void k_abcd_rows(
    const unsigned short* __restrict__ fsnb, const int* __restrict__ bd,
    const float* __restrict__ pos, float* __restrict__ rowloss) {
  __shared__ __align__(16) unsigned short Ab[64 * 64];
  __shared__ __align__(16) unsigned short Bb[256 * 64];
  __shared__ float mrg[64][4][2];
  int b = blockIdx.x >> 2, nb = blockIdx.x & 3;
  int n0 = nb * 64;
  int t = threadIdx.x, w = t >> 6, lane = t & 63, quad = lane >> 4, l15 = lane & 15;
  f32x4 acc[4][4];
  const f32x4 fz = {0.f, 0.f, 0.f, 0.f};
#pragma unroll
  for (int i = 0; i < 4; ++i)
#pragma unroll
    for (int j = 0; j < 4; ++j) acc[i][j] = fz;
  const unsigned short* fb = fsnb + (size_t)b * 256 * 256;

  for (int kc = 0; kc < 4; ++kc) {
    {
      int r = t >> 2, cc = (t & 3) * 16;
      const uint4* s = (const uint4*)(const void*)(fb + (size_t)(n0 + r) * 256 + kc * 64 + cc);
      *(uint4*)(void*)(Ab + r * 64 + cc) = s[0];
      *(uint4*)(void*)(Ab + r * 64 + cc + 8) = s[1];
    }
#pragma unroll
    for (int it = 0; it < 4; ++it) {
      int m = it * 64 + (t >> 2), cc = (t & 3) * 16;
      const uint4* s = (const uint4*)(const void*)(fb + (size_t)m * 256 + kc * 64 + cc);
      *(uint4*)(void*)(Bb + m * 64 + cc) = s[0];
      *(uint4*)(void*)(Bb + m * 64 + cc + 8) = s[1];
    }
    __syncthreads();
#pragma unroll
    for (int s = 0; s < 2; ++s) {
      s16x8 af[4], bf[4];
#pragma unroll
      for (int i = 0; i < 4; ++i) {
        af[i] = *(const s16x8*)(const void*)(Ab + (i * 16 + l15) * 64 + s * 32 + quad * 8);
        bf[i] = *(const s16x8*)(const void*)(Bb + (w * 64 + i * 16 + l15) * 64 + s * 32 + quad * 8);
      }
#pragma unroll
      for (int i = 0; i < 4; ++i)
#pragma unroll
        for (int j = 0; j < 4; ++j)
          acc[i][j] = __builtin_amdgcn_mfma_f32_16x16x32_bf16(af[i], bf[j], acc[i][j], 0, 0, 0);
    }
    __syncthreads();
  }

  int nbmask[4];
#pragma unroll
  for (int j = 0; j < 4; ++j) nbmask[j] = bd[b * 256 + w * 64 + j * 16 + l15];
#pragma unroll
  for (int i = 0; i < 4; ++i) {
#pragma unroll
    for (int r = 0; r < 4; ++r) {
      float mxv = -1e30f, se = 0.f;
#pragma unroll
      for (int j = 0; j < 4; ++j) {
        float v = nbmask[j] ? -1e30f : (acc[i][j][r] / 0.1f);
        if (v > mxv) {
          se = se * expf(mxv - v) + 1.f;
          mxv = v;
        } else {
          se += expf(v - mxv);
        }
      }
#pragma unroll
      for (int msk = 1; msk < 16; msk <<= 1) {
        float omx = __shfl_xor(mxv, msk, 64);
        float ose = __shfl_xor(se, msk, 64);
        float nm = fmaxf(mxv, omx);
        se = se * expf(mxv - nm) + ose * expf(omx - nm);
        mxv = nm;
      }
      if (l15 == 0) {
        mrg[i * 16 + quad * 4 + r][w][0] = mxv;
        mrg[i * 16 + quad * 4 + r][w][1] = se;
      }
    }
  }
  __syncthreads();
  if (t < 64) {
    float MX = -1e30f, SE = 0.f;
    for (int ww = 0; ww < 4; ++ww) {
      float omx = mrg[t][ww][0], ose = mrg[t][ww][1];
      float nm = fmaxf(MX, omx);
      SE = SE * expf(MX - nm) + ose * expf(omx - nm);
      MX = nm;
    }
    float p = pos[b * 256 + n0 + t];
    float nm = fmaxf(MX, p);
    float se2 = SE * expf(MX - nm) + expf(p - nm);
    rowloss[b * 256 + n0 + t] = nm + logf(se2) - p;
  }
}

// --------------------------- K8a: gafd reduction ---------------------------
__global__ void k_gafd(const float* __restrict__ fsn, const float* __restrict__ ftn,
                       float* __restrict__ gsum) {
  __shared__ float l4[4];
  int i = blockIdx.x * 256 + threadIdx.x;
  const float4* A = (const float4*)fsn;
  const float4* Bp = (const float4*)ftn;
  float4 x = A[i], y = Bp[i];
  float d0 = x.x - y.x, d1 = x.y - y.y, d2 = x.z - y.z, d3 = x.w - y.w;
  float s = d0 * d0 + d1 * d1 + d2 * d2 + d3 * d3;
  s = block_sum(s, l4);
  if (threadIdx.x == 0) atomicAdd(gsum, s);
}

// --------------------------- K8b: final scalars ----------------------------
__global__ void k_final(const float* __restrict__ gsum, const float* __restrict__ rowloss,
                        const int* __restrict__ bd, const int* __restrict__ cnt,
                        const int* __restrict__ nbc, float* __restrict__ out) {
  __shared__ float l4[4];
  int t = threadIdx.x;
  float abcd_acc = 0.f, vnum = 0.f;
  for (int b = 0; b < 16; ++b) {
    float c = bd[b * 256 + t] ? rowloss[b * 256 + t] : 0.f;
    float s = block_sum(c, l4);
    if (t == 0) {
      float cb = (float)cnt[b];
      float per = s / fmaxf(cb, 1.f);
      if (cnt[b] > 0 && nbc[b] > 0) {
        abcd_acc += per;
        vnum += 1.f;
      }
    }
  }
  if (t == 0) {
    float gafd = gsum[0] / 1048576.f;
    float abcd = vnum > 0.f ? abcd_acc / fmaxf(vnum, 1.f) : 0.f;
    out[0] = gafd + 0.5f * abcd;
    out[1] = gafd;
    out[2] = abcd;
  }
}

// --------------------------- workspace layout ------------------------------
static constexpr size_t OFF_TPAD = 0;
static constexpr size_t TPAD_BYTES = (size_t)16 * 66 * 66 * 1024 * 2;  // 142,737,408
static constexpr size_t OFF_WT = OFF_TPAD + TPAD_BYTES;
static constexpr size_t WT_BYTES = (size_t)9 * 16 * 512 * 64 * 2;      // 9,437,184
static constexpr size_t OFF_HEAT = OFF_WT + WT_BYTES;
static constexpr size_t OFF_GSUM = OFF_HEAT + 262144;
static constexpr size_t OFF_HM = OFF_GSUM + 256;
static constexpr size_t OFF_SC = OFF_HM + 262144;
static constexpr size_t OFF_IDX = OFF_SC + 262144;
static constexpr size_t OFF_FT = OFF_IDX + 16384;
static constexpr size_t OFF_FS = OFF_FT + (size_t)16 * 256 * 1024 * 4;
static constexpr size_t OFF_FTN = OFF_FS + (size_t)16 * 256 * 512 * 4;
static constexpr size_t OFF_FSN = OFF_FTN + (size_t)16 * 256 * 256 * 4;
static constexpr size_t OFF_FSNB = OFF_FSN + (size_t)16 * 256 * 256 * 4;
static constexpr size_t OFF_POS = OFF_FSNB + (size_t)16 * 256 * 256 * 2;
static constexpr size_t OFF_BD = OFF_POS + 16384;
static constexpr size_t OFF_CNT = OFF_BD + 16384;
static constexpr size_t OFF_NBC = OFF_CNT + 64;
static constexpr size_t OFF_RL = OFF_NBC + 64;

extern "C" void kernel_launch(void* const* d_in, const int* in_sizes, int n_in,
                              void* d_out, int out_size, void* d_ws, size_t ws_size,
                              hipStream_t stream) {
  const float* teacher = (const float*)d_in[0];
  const float* student = (const float*)d_in[1];
  const float* w1 = (const float*)d_in[2];
  const float* b1 = (const float*)d_in[3];
  const float* w2 = (const float*)d_in[4];
  const float* b2 = (const float*)d_in[5];
  const float* t_w = (const float*)d_in[6];
  const float* t_b = (const float*)d_in[7];
  const float* t_g = (const float*)d_in[8];
  const float* t_be = (const float*)d_in[9];
  const float* s_w = (const float*)d_in[10];
  const float* s_b = (const float*)d_in[11];
  const float* s_g = (const float*)d_in[12];
  const float* s_be = (const float*)d_in[13];
  float* out = (float*)d_out;

  char* ws = (char*)d_ws;
  unsigned short* tpad = (unsigned short*)(ws + OFF_TPAD);
  unsigned short* wt = (unsigned short*)(ws + OFF_WT);
  float* heat = (float*)(ws + OFF_HEAT);
  float* gsum = (float*)(ws + OFF_GSUM);
  float* hm = (float*)(ws + OFF_HM);
  float* scores = (float*)(ws + OFF_SC);
  int* idx_sel = (int*)(ws + OFF_IDX);
  float* ftbuf = (float*)(ws + OFF_FT);
  float* fsbuf = (float*)(ws + OFF_FS);
  float* ftn = (float*)(ws + OFF_FTN);
  float* fsn = (float*)(ws + OFF_FSN);
  unsigned short* fsnb = (unsigned short*)(ws + OFF_FSNB);
  float* pos = (float*)(ws + OFF_POS);
  int* bd = (int*)(ws + OFF_BD);
  int* cnt = (int*)(ws + OFF_CNT);
  int* nbc = (int*)(ws + OFF_NBC);
  float* rowloss = (float*)(ws + OFF_RL);

  hipMemsetAsync(tpad, 0, TPAD_BYTES, stream);          // zero pad borders
  hipMemsetAsync(ws + OFF_HEAT, 0, 262144 + 256, stream);  // heat + gsum

  k_pad_transpose<<<16384, 256, 0, stream>>>(teacher, tpad);
  k_wprep<<<18432, 256, 0, stream>>>(w1, wt);
  k_conv<<<2048, 256, 0, stream>>>(tpad, wt, b1, w2, heat);
  k_heat2score<<<16, 256, 0, stream>>>(heat, b2, out + 3, hm, scores);
  k_topk<<<16, 256, 0, stream>>>(scores, idx_sel);
  k_gather<<<4096, 256, 0, stream>>>(teacher, 1024, idx_sel, ftbuf);
  k_gather<<<4096, 256, 0, stream>>>(student, 512, idx_sel, fsbuf);
  k_proj_ln<<<512, 256, 0, stream>>>(ftbuf, 1024, t_w, t_b, t_g, t_be, ftn, (unsigned short*)nullptr);
  k_proj_ln<<<512, 256, 0, stream>>>(fsbuf, 512, s_w, s_b, s_g, s_be, fsn, fsnb);
  k_sal_pos<<<16, 256, 0, stream>>>(hm, idx_sel, ftn, fsn, bd, pos, cnt, nbc);
  k_abcd_rows<<<64, 256, 0, stream>>>(fsnb, bd, pos, rowloss);
  k_gafd<<<1024, 256, 0, stream>>>(fsn, ftn, gsum);
  k_final<<<1, 256, 0, stream>>>(gsum, rowloss, bd, cnt, nbc, out);
}

// Round 2
// 1429.860 us; speedup vs baseline: 1.6686x; 1.6686x over previous
//
#include <hip/hip_runtime.h>
#include <stdint.h>

// ---------------------------------------------------------------------------
// GAFD_ABCD pipeline on MI355X.  R2: radix-select topk, coalesced gathers,
// MFMA projection GEMM, in-kernel pad borders (drop 142MB memset).
// ---------------------------------------------------------------------------

typedef float f32x4 __attribute__((ext_vector_type(4)));
typedef short s16x8 __attribute__((ext_vector_type(8)));

__device__ __forceinline__ unsigned short f2bf(float f) {
  unsigned u = __float_as_uint(f);
  u += 0x7fffu + ((u >> 16) & 1u);   // RNE
  return (unsigned short)(u >> 16);
}
__device__ __forceinline__ float bf2f(unsigned short h) {
  return __uint_as_float((unsigned)h << 16);
}

__device__ __forceinline__ void gld16(const void* g, void* l) {
  __builtin_amdgcn_global_load_lds(
      (const __attribute__((address_space(1))) void*)g,
      (__attribute__((address_space(3))) void*)l, 16, 0, 0);
}

__device__ __forceinline__ float block_sum(float v, float* l4) {
  for (int m = 32; m; m >>= 1) v += __shfl_xor(v, m, 64);
  int wid = threadIdx.x >> 6;
  if ((threadIdx.x & 63) == 0) l4[wid] = v;
  __syncthreads();
  float r = l4[0] + l4[1] + l4[2] + l4[3];
  __syncthreads();
  return r;
}

// --------------------------- K0: pad-transpose + borders -------------------
// teacher [16,1024,64,64] f32 -> tpad [16][66][66][1024] bf16, borders zeroed
// in-kernel (no memset needed).
__global__ void k_pad_transpose(const float* __restrict__ teacher,
                                unsigned short* __restrict__ tpad) {
  __shared__ __align__(16) unsigned short lds[64 * 65];
  int bid = blockIdx.x;
  int cb = bid & 15, y = (bid >> 4) & 63, b = bid >> 10;
  int t = threadIdx.x;
#pragma unroll
  for (int it = 0; it < 16; ++it) {
    int idx = it * 256 + t;
    int cl = idx >> 6, x = idx & 63;
    float v = teacher[(size_t)(b * 1024 + cb * 64 + cl) * 4096 + y * 64 + x];
    lds[cl * 65 + x] = f2bf(v);
  }
  __syncthreads();
  size_t obase = ((size_t)(b * 66 + y + 1) * 66 + 1) * 1024 + cb * 64;
#pragma unroll
  for (int it = 0; it < 16; ++it) {
    int x = it * 4 + (t >> 6);
    int cl = t & 63;
    tpad[obase + (size_t)x * 1024 + cl] = lds[cl * 65 + x];
  }
  // borders (this block's 64 channels):
  if (y == 0) {
    for (int idx = t; idx < 66 * 64; idx += 256) {
      int col = idx >> 6, cl = idx & 63;
      tpad[((size_t)(b * 66) * 66 + col) * 1024 + cb * 64 + cl] = 0;
    }
  }
  if (y == 63) {
    for (int idx = t; idx < 66 * 64; idx += 256) {
      int col = idx >> 6, cl = idx & 63;
      tpad[((size_t)(b * 66 + 65) * 66 + col) * 1024 + cb * 64 + cl] = 0;
    }
  }
  if (t < 128) {
    int col = (t >= 64) ? 65 : 0;
    int cl = t & 63;
    tpad[((size_t)(b * 66 + y + 1) * 66 + col) * 1024 + cb * 64 + cl] = 0;
  }
}

// --------------------------- K0b: conv weight prep -------------------------
// conv1_w [co=512][ci=1024][ky][kx] -> wt[tap][kb][co 512][kc 64] bf16
__global__ void k_wprep(const float* __restrict__ w1,
                        unsigned short* __restrict__ wt) {
  int e = blockIdx.x * 256 + threadIdx.x;
  int kc = e & 63;
  int co = (e >> 6) & 511;
  int kb = (e >> 15) & 15;
  int tap = e >> 19;
  if (tap >= 9) return;
  float v = w1[(size_t)(co * 1024 + kb * 64 + kc) * 9 + tap];
  wt[e] = f2bf(v);
}

// --------------------------- K0c: proj weight transpose --------------------
// w [K][256] f32 -> wT [256][K] bf16
__global__ void k_wT(const float* __restrict__ w, unsigned short* __restrict__ wT,
                     int K) {
  int e = blockIdx.x * 256 + threadIdx.x;  // < 256*K
  int p = e / K, k = e - p * K;
  wT[e] = f2bf(w[(size_t)k * 256 + p]);
}

// --------------------------- K1: conv GEMM ---------------------------------
__global__ __launch_bounds__(256) void k_conv(
    const unsigned short* __restrict__ tpad, const unsigned short* __restrict__ wt,
    const float* __restrict__ b1, const float* __restrict__ w2,
    float* __restrict__ heat) {
  __shared__ __align__(16) unsigned short As[128 * 64];
  __shared__ __align__(16) unsigned short Bs[128 * 64];
  int bid = blockIdx.x;
  int nt = bid & 3, mt = bid >> 2;
  int p0 = mt * 128;
  int b = p0 >> 12, y0 = (p0 >> 6) & 63;
  int co0 = nt * 128;
  int t = threadIdx.x, wid = t >> 6, lane = t & 63;
  int wm = wid & 1, wn = wid >> 1;
  int quad = lane >> 4, l15 = lane & 15;

  f32x4 acc[4][4];
  const f32x4 fz = {0.f, 0.f, 0.f, 0.f};
#pragma unroll
  for (int i = 0; i < 4; ++i)
#pragma unroll
    for (int j = 0; j < 4; ++j) acc[i][j] = fz;

  int xj[4], yrj[4];
#pragma unroll
  for (int jj = 0; jj < 4; ++jj) {
    int m = (wid * 4 + jj) * 8 + (lane >> 3);
    xj[jj] = m & 63;
    yrj[jj] = m >> 6;
  }
  int kcol = (lane & 7) * 8;
  const unsigned short* wt_nt = wt + (size_t)co0 * 64;

  for (int tap = 0; tap < 9; ++tap) {
    int ky = tap / 3, kx = tap - ky * 3;
    size_t abase[4];
#pragma unroll
    for (int jj = 0; jj < 4; ++jj) {
      int row = y0 + yrj[jj] + ky;
      int col = xj[jj] + kx;
      abase[jj] = ((size_t)(b * 66 + row) * 66 + col) * 1024 + kcol;
    }
    size_t bbase = (size_t)tap * 16 * 32768;
    for (int kb = 0; kb < 16; ++kb) {
#pragma unroll
      for (int jj = 0; jj < 4; ++jj) {
        gld16(tpad + abase[jj] + kb * 64, (char*)As + (wid * 4 + jj) * 1024);
        gld16(wt_nt + bbase + (size_t)kb * 32768 + (wid * 4 + jj) * 512 + lane * 8,
              (char*)Bs + (wid * 4 + jj) * 1024);
      }
      __syncthreads();
#pragma unroll
      for (int s = 0; s < 2; ++s) {
        s16x8 af[4], bf[4];
#pragma unroll
        for (int i = 0; i < 4; ++i) {
          af[i] = *(const s16x8*)(const void*)(As + (wm * 64 + i * 16 + l15) * 64 + s * 32 + quad * 8);
          bf[i] = *(const s16x8*)(const void*)(Bs + (wn * 64 + i * 16 + l15) * 64 + s * 32 + quad * 8);
        }
#pragma unroll
        for (int i = 0; i < 4; ++i)
#pragma unroll
          for (int j = 0; j < 4; ++j)
            acc[i][j] = __builtin_amdgcn_mfma_f32_16x16x32_bf16(af[i], bf[j], acc[i][j], 0, 0, 0);
      }
      __syncthreads();
    }
  }

  float w2v[4], b1v[4];
#pragma unroll
  for (int j = 0; j < 4; ++j) {
    int co = co0 + wn * 64 + j * 16 + l15;
    w2v[j] = w2[co];
    b1v[j] = b1[co];
  }
#pragma unroll
  for (int i = 0; i < 4; ++i) {
#pragma unroll
    for (int r = 0; r < 4; ++r) {
      float part = 0.f;
#pragma unroll
      for (int j = 0; j < 4; ++j) {
        float v = acc[i][j][r] + b1v[j];
        v = fmaxf(v, 0.f);
        part += v * w2v[j];
      }
#pragma unroll
      for (int msk = 1; msk < 16; msk <<= 1) part += __shfl_xor(part, msk, 64);
      if (l15 == 0) {
        int m = wm * 64 + i * 16 + quad * 4 + r;
        atomicAdd(&heat[p0 + m], part);
      }
    }
  }
}

// --------------------------- threefry (JAX partitionable) ------------------
__device__ __forceinline__ unsigned rotl32(unsigned x, int d) {
  return (x << d) | (x >> (32 - d));
}
__device__ unsigned threefry_bits(unsigned lo) {
  const unsigned k0 = 0u, k1 = 42u;
  const unsigned k2 = 0x1BD11BDAu ^ k0 ^ k1;
  unsigned x0 = 0u + k0, x1 = lo + k1;
#define TF_R4(a, bq, c, d)                                \
  x0 += x1; x1 = rotl32(x1, a); x1 ^= x0;                 \
  x0 += x1; x1 = rotl32(x1, bq); x1 ^= x0;                \
  x0 += x1; x1 = rotl32(x1, c); x1 ^= x0;                 \
  x0 += x1; x1 = rotl32(x1, d); x1 ^= x0;
  TF_R4(13, 15, 26, 6)  x0 += k1; x1 += k2 + 1u;
  TF_R4(17, 29, 16, 24) x0 += k2; x1 += k0 + 2u;
  TF_R4(13, 15, 26, 6)  x0 += k0; x1 += k1 + 3u;
  TF_R4(17, 29, 16, 24) x0 += k1; x1 += k2 + 4u;
  TF_R4(13, 15, 26, 6)  x0 += k2; x1 += k0 + 5u;
#undef TF_R4
  return x0 ^ x1;
}

// --------------------------- K2: softplus / prob / scores ------------------
__global__ void k_heat2score(const float* __restrict__ heat, const float* __restrict__ b2p,
                             float* __restrict__ out_hm, float* __restrict__ hm,
                             float* __restrict__ scores) {
  __shared__ float l4[4];
  int b = blockIdx.x, t = threadIdx.x;
  float b2 = b2p[0];
  float hv[16];
  float lsum = 0.f;
#pragma unroll
  for (int j = 0; j < 16; ++j) {
    int e = j * 256 + t;
    float x = heat[b * 4096 + e] + b2;
    float sp = fmaxf(x, 0.f) + log1pf(expf(-fabsf(x)));
    hv[j] = sp;
    lsum += sp;
  }
  float S = block_sum(lsum, l4);
  float denom = S + 1e-6f;
#pragma unroll
  for (int j = 0; j < 16; ++j) {
    int e = j * 256 + t;
    float sp = hv[j];
    out_hm[b * 4096 + e] = sp;
    hm[b * 4096 + e] = sp;
    float lp = logf(sp / denom + 1e-12f);
    unsigned bits = threefry_bits((unsigned)(b * 4096 + e));
    float u01 = __uint_as_float((bits >> 9) | 0x3f800000u) - 1.0f;
    float u = fmaxf(1e-8f, u01 * (1.0f - 1e-8f) + 1e-8f);
    float gum = -logf(-logf(u));
    scores[b * 4096 + e] = lp + gum;
  }
}

// --------------------------- K3: exact top-256 via radix select ------------
// Set-equivalent to lax.top_k (downstream is permutation-invariant).
__global__ void k_topk(const float* __restrict__ scores, int* __restrict__ idx_sel) {
  __shared__ unsigned keys[4096];
  __shared__ unsigned hist[256];
  __shared__ unsigned suf[256];
  __shared__ unsigned sel[2];
  __shared__ int wpos;
  int b = blockIdx.x, t = threadIdx.x;
#pragma unroll
  for (int j = 0; j < 16; ++j) {
    unsigned u = __float_as_uint(scores[b * 4096 + j * 256 + t]);
    u = (u >> 31) ? ~u : (u | 0x80000000u);
    keys[j * 256 + t] = u;
  }
  if (t == 0) wpos = 0;
  unsigned prefix = 0, hmask = 0, r = 256;
  for (int pass = 0; pass < 4; ++pass) {
    int shift = 24 - 8 * pass;
    hist[t] = 0;
    __syncthreads();
#pragma unroll
    for (int j = 0; j < 16; ++j) {
      unsigned u = keys[j * 256 + t];
      if ((u & hmask) == prefix) atomicAdd(&hist[(u >> shift) & 255u], 1u);
    }
    __syncthreads();
    suf[t] = hist[t];
    __syncthreads();
    for (int off = 1; off < 256; off <<= 1) {
      unsigned v = (t + off < 256) ? suf[t + off] : 0u;
      __syncthreads();
      suf[t] += v;
      __syncthreads();
    }
    unsigned above = (t < 255) ? suf[t + 1] : 0u;
    if (suf[t] >= r && above < r) {
      sel[0] = (unsigned)t;
      sel[1] = above;
    }
    __syncthreads();
    prefix |= sel[0] << shift;
    hmask |= 0xFFu << shift;
    r -= sel[1];
    __syncthreads();
  }
  // prefix == threshold key T; take all > T, then r of == T.
#pragma unroll
  for (int j = 0; j < 16; ++j) {
    int e = j * 256 + t;
    if (keys[e] > prefix) {
      int s = atomicAdd(&wpos, 1);
      idx_sel[b * 256 + s] = e;
    }
  }
  __syncthreads();
#pragma unroll
  for (int j = 0; j < 16; ++j) {
    int e = j * 256 + t;
    if (keys[e] == prefix) {
      int s = atomicAdd(&wpos, 1);
      if (s < 256) idx_sel[b * 256 + s] = e;
    }
  }
}

// --------------------------- K4a: teacher gather from tpad (coalesced) -----
// out ftb [b*256+n][1024] bf16
__global__ void k_gather_t(const unsigned short* __restrict__ tpad,
                           const int* __restrict__ idx_sel,
                           unsigned short* __restrict__ ftb) {
  int bn = blockIdx.x;
  int b = bn >> 8;
  int idx = idx_sel[bn];
  int px = idx & 63, py = idx >> 6;
  // taps at padded coords (py,px),(py,px+1),(py+1,px),(py+1,px+1)
  const unsigned short* base = tpad + ((size_t)(b * 66 + py) * 66 + px) * 1024;
  for (int c = threadIdx.x; c < 1024; c += 256) {
    float v = bf2f(base[c]) + bf2f(base[c + 1024]) +
              bf2f(base[c + 66 * 1024]) + bf2f(base[c + 67 * 1024]);
    ftb[(size_t)bn * 1024 + c] = f2bf(0.25f * v);
  }
}

// --------------------------- K4b: student gather (plane-local + LDS) -------
// out fsb [b*256+n][512] bf16
__global__ void k_gather_s(const float* __restrict__ student,
                           const int* __restrict__ idx_sel,
                           unsigned short* __restrict__ fsb) {
  __shared__ unsigned short tile[32][258];
  int blk = blockIdx.x;
  int b = blk >> 4, c0 = (blk & 15) * 32;
  int t = threadIdx.x;
  int idx = idx_sel[b * 256 + t];
  int px = idx & 63, py = idx >> 6;
  const float* sb = student + ((size_t)b * 512 + c0) * 4096;
  for (int cc = 0; cc < 32; ++cc) {
    const float* pc = sb + (size_t)cc * 4096;
    float v = 0.f;
    if (py > 0) {
      if (px > 0) v += pc[(py - 1) * 64 + px - 1];
      v += pc[(py - 1) * 64 + px];
    }
    if (px > 0) v += pc[py * 64 + px - 1];
    v += pc[py * 64 + px];
    tile[cc][t] = f2bf(0.25f * v);
  }
  __syncthreads();
  for (int it = 0; it < 32; ++it) {
    int n = it * 8 + (t >> 5), cc = t & 31;
    fsb[(size_t)(b * 256 + n) * 512 + c0 + cc] = tile[cc][n];
  }
}

// --------------------------- K5: projection GEMM (MFMA) --------------------
// A [4096][K] bf16, Wt [256][K] bf16 -> out [4096][256] f32. Grid (M/128)*2.
__global__ __launch_bounds__(256) void k_proj(
    const unsigned short* __restrict__ A, const unsigned short* __restrict__ Wt,
    int K, float* __restrict__ outp) {
  __shared__ __align__(16) unsigned short As[128 * 64];
  __shared__ __align__(16) unsigned short Bs[128 * 64];
  int bid = blockIdx.x;
  int nt = bid & 1, mt = bid >> 1;
  int m0 = mt * 128, n0 = nt * 128;
  int t = threadIdx.x, wid = t >> 6, lane = t & 63;
  int wm = wid & 1, wn = wid >> 1;
  int quad = lane >> 4, l15 = lane & 15;

  f32x4 acc[4][4];
  const f32x4 fz = {0.f, 0.f, 0.f, 0.f};
#pragma unroll
  for (int i = 0; i < 4; ++i)
#pragma unroll
    for (int j = 0; j < 4; ++j) acc[i][j] = fz;

  int row4[4];
#pragma unroll
  for (int jj = 0; jj < 4; ++jj) row4[jj] = (wid * 4 + jj) * 8 + (lane >> 3);
  int kcol = (lane & 7) * 8;

  int nkb = K >> 6;
  for (int kb = 0; kb < nkb; ++kb) {
#pragma unroll
    for (int jj = 0; jj < 4; ++jj) {
      gld16(A + (size_t)(m0 + row4[jj]) * K + kb * 64 + kcol,
            (char*)As + (wid * 4 + jj) * 1024);
      gld16(Wt + (size_t)(n0 + row4[jj]) * K + kb * 64 + kcol,
            (char*)Bs + (wid * 4 + jj) * 1024);
    }
    __syncthreads();
#pragma unroll
    for (int s = 0; s < 2; ++s) {
      s16x8 af[4], bf[4];
#pragma unroll
      for (int i = 0; i < 4; ++i) {
        af[i] = *(const s16x8*)(const void*)(As + (wm * 64 + i * 16 + l15) * 64 + s * 32 + quad * 8);
        bf[i] = *(const s16x8*)(const void*)(Bs + (wn * 64 + i * 16 + l15) * 64 + s * 32 + quad * 8);
      }
#pragma unroll
      for (int i = 0; i < 4; ++i)
#pragma unroll
        for (int j = 0; j < 4; ++j)
          acc[i][j] = __builtin_amdgcn_mfma_f32_16x16x32_bf16(af[i], bf[j], acc[i][j], 0, 0, 0);
    }
    __syncthreads();
  }
#pragma unroll
  for (int i = 0; i < 4; ++i)
#pragma unroll
    for (int j = 0; j < 4; ++j)
#pragma unroll
      for (int r = 0; r < 4; ++r) {
        int m = m0 + wm * 64 + i * 16 + quad * 4 + r;
        int p = n0 + wn * 64 + j * 16 + l15;
        outp[(size_t)m * 256 + p] = acc[i][j][r];
      }
}

// --------------------------- K5b: bias + LN + l2norm -----------------------
__global__ void k_ln(const float* __restrict__ projp, const float* __restrict__ bias,
                     const float* __restrict__ g, const float* __restrict__ beta,
                     float* __restrict__ outf, unsigned short* __restrict__ outb) {
  __shared__ float l4[4];
  int row = blockIdx.x, t = threadIdx.x;
  float x = projp[(size_t)row * 256 + t] + bias[t];
  float s1 = block_sum(x, l4);
  float mu = s1 * (1.f / 256.f);
  float d = x - mu;
  float s2 = block_sum(d * d, l4);
  float rstd = rsqrtf(s2 * (1.f / 256.f) + 1e-5f);
  float xn = d * rstd * g[t] + beta[t];
  float ss = block_sum(xn * xn, l4);
  float o = xn / fmaxf(sqrtf(ss), 1e-12f);
  outf[(size_t)row * 256 + t] = o;
  if (outb) outb[(size_t)row * 256 + t] = f2bf(o);
}

// --------------------------- K6: saliency / bd ----------------------------
__global__ void k_sal(const float* __restrict__ hm, const int* __restrict__ idx_sel,
                      int* __restrict__ bd, int* __restrict__ cnt, int* __restrict__ nbc) {
  __shared__ float l4[4];
  int b = blockIdx.x, t = threadIdx.x;
  int idx = idx_sel[b * 256 + t];
  int px = idx & 63, py = idx >> 6;
  const float* hb = hm + b * 4096;
  float v = 0.f;
  if (py > 0) {
    if (px > 0) v += hb[(py - 1) * 64 + px - 1];
    v += hb[(py - 1) * 64 + px];
  }
  if (px > 0) v += hb[py * 64 + px - 1];
  v += hb[py * 64 + px];
  float sal = 0.25f * v;
  float mx = sal;
  for (int m = 32; m; m >>= 1) mx = fmaxf(mx, __shfl_xor(mx, m, 64));
  if ((t & 63) == 0) l4[t >> 6] = mx;
  __syncthreads();
  mx = fmaxf(fmaxf(l4[0], l4[1]), fmaxf(l4[2], l4[3]));
  __syncthreads();
  int bdv = sal > 0.6f * mx ? 1 : 0;
  bd[b * 256 + t] = bdv;
  float c = block_sum((float)bdv, l4);
  if (t == 0) {
    cnt[b] = (int)c;
    nbc[b] = 256 - (int)c;
  }
}

// --------------------------- K6b: pos + gafd (coalesced per-row) -----------
__global__ void k_pos_gafd(const float* __restrict__ fsn, const float* __restrict__ ftn,
                           float* __restrict__ pos, float* __restrict__ gsum) {
  __shared__ float l4[4];
  int row = blockIdx.x, t = threadIdx.x;
  float a = fsn[(size_t)row * 256 + t];
  float bt = ftn[(size_t)row * 256 + t];
  float sdot = block_sum(a * bt, l4);
  if (t == 0) pos[row] = sdot * 10.f;  // / TAU
  float d = a - bt;
  float ssq = block_sum(d * d, l4);
  if (t == 0) atomicAdd(gsum, ssq);
}

// --------------------------- K7: neg matrix + masked LSE -------------------
__global__ __launch_bounds__(256) void k_abcd_rows(
    const unsigned short* __restrict__ fsnb, const int* __restrict__ bd,
    const float* __restrict__ pos, float* __restrict__ rowloss) {
  __shared__ __align__(16) unsigned short Ab[64 * 64];
  __shared__ __align__(16) unsigned short Bb[256 * 64];
  __shared__ float mrg[64][4][2];
  int b = blockIdx.x >> 2, nb = blockIdx.x & 3;
  int n0 = nb * 64;
  int t = threadIdx.x, w = t >> 6, lane = t & 63, quad = lane >> 4, l15 = lane & 15;
  f32x4 acc[4][4];
  const f32x4 fz = {0.f, 0.f, 0.f, 0.f};
#pragma unroll
  for (int i = 0; i < 4; ++i)
#pragma unroll
    for (int j = 0; j < 4; ++j) acc[i][j] = fz;
  const unsigned short* fb = fsnb + (size_t)b * 256 * 256;

  for (int kc = 0; kc < 4; ++kc) {
    {
      int r = t >> 2, cc = (t & 3) * 16;
      const uint4* s = (const uint4*)(const void*)(fb + (size_t)(n0 + r) * 256 + kc * 64 + cc);
      *(uint4*)(void*)(Ab + r * 64 + cc) = s[0];
      *(uint4*)(void*)(Ab + r * 64 + cc + 8) = s[1];
    }
#pragma unroll
    for (int it = 0; it < 4; ++it) {
      int m = it * 64 + (t >> 2), cc = (t & 3) * 16;
      const uint4* s = (const uint4*)(const void*)(fb + (size_t)m * 256 + kc * 64 + cc);
      *(uint4*)(void*)(Bb + m * 64 + cc) = s[0];
      *(uint4*)(void*)(Bb + m * 64 + cc + 8) = s[1];
    }
    __syncthreads();
#pragma unroll
    for (int s = 0; s < 2; ++s) {
      s16x8 af[4], bf[4];
#pragma unroll
      for (int i = 0; i < 4; ++i) {
        af[i] = *(const s16x8*)(const void*)(Ab + (i * 16 + l15) * 64 + s * 32 + quad * 8);
        bf[i] = *(const s16x8*)(const void*)(Bb + (w * 64 + i * 16 + l15) * 64 + s * 32 + quad * 8);
      }
#pragma unroll
      for (int i = 0; i < 4; ++i)
#pragma unroll
        for (int j = 0; j < 4; ++j)
          acc[i][j] = __builtin_amdgcn_mfma_f32_16x16x32_bf16(af[i], bf[j], acc[i][j], 0, 0, 0);
    }
    __syncthreads();
  }

  int nbmask[4];
#pragma unroll
  for (int j = 0; j < 4; ++j) nbmask[j] = bd[b * 256 + w * 64 + j * 16 + l15];
#pragma unroll
  for (int i = 0; i < 4; ++i) {
#pragma unroll
    for (int r = 0; r < 4; ++r) {
      float mxv = -1e30f, se = 0.f;
#pragma unroll
      for (int j = 0; j < 4; ++j) {
        float v = nbmask[j] ? -1e30f : (acc[i][j][r] / 0.1f);
        if (v > mxv) {
          se = se * expf(mxv - v) + 1.f;
          mxv = v;
        } else {
          se += expf(v - mxv);
        }
      }
#pragma unroll
      for (int msk = 1; msk < 16; msk <<= 1) {
        float omx = __shfl_xor(mxv, msk, 64);
        float ose = __shfl_xor(se, msk, 64);
        float nm = fmaxf(mxv, omx);
        se = se * expf(mxv - nm) + ose * expf(omx - nm);
        mxv = nm;
      }
      if (l15 == 0) {
        mrg[i * 16 + quad * 4 + r][w][0] = mxv;
        mrg[i * 16 + quad * 4 + r][w][1] = se;
      }
    }
  }
  __syncthreads();
  if (t < 64) {
    float MX = -1e30f, SE = 0.f;
    for (int ww = 0; ww < 4; ++ww) {
      float omx = mrg[t][ww][0], ose = mrg[t][ww][1];
      float nm = fmaxf(MX, omx);
      SE = SE * expf(MX - nm) + ose * expf(omx - nm);
      MX = nm;
    }
    float p = pos[b * 256 + n0 + t];
    float nm = fmaxf(MX, p);
    float se2 = SE * expf(MX - nm) + expf(p - nm);
    rowloss[b * 256 + n0 + t] = nm + logf(se2) - p;
  }
}

// --------------------------- K8: final scalars -----------------------------
__global__ void k_final(const float* __restrict__ gsum, const float* __restrict__ rowloss,
                        const int* __restrict__ bd, const int* __restrict__ cnt,
                        const int* __restrict__ nbc, float* __restrict__ out) {
  __shared__ float l4[4];
  int t = threadIdx.x;
  float abcd_acc = 0.f, vnum = 0.f;
  for (int b = 0; b < 16; ++b) {
    float c = bd[b * 256 + t] ? rowloss[b * 256 + t] : 0.f;
    float s = block_sum(c, l4);
    if (t == 0) {
      float cb = (float)cnt[b];
      float per = s / fmaxf(cb, 1.f);
      if (cnt[b] > 0 && nbc[b] > 0) {
        abcd_acc += per;
        vnum += 1.f;
      }
    }
  }
  if (t == 0) {
    float gafd = gsum[0] / 1048576.f;
    float abcd = vnum > 0.f ? abcd_acc / fmaxf(vnum, 1.f) : 0.f;
    out[0] = gafd + 0.5f * abcd;
    out[1] = gafd;
    out[2] = abcd;
  }
}

// --------------------------- workspace layout ------------------------------
static constexpr size_t OFF_TPAD = 0;
static constexpr size_t TPAD_BYTES = (size_t)16 * 66 * 66 * 1024 * 2;
static constexpr size_t OFF_WT = OFF_TPAD + TPAD_BYTES;
static constexpr size_t WT_BYTES = (size_t)9 * 16 * 512 * 64 * 2;
static constexpr size_t OFF_HEAT = OFF_WT + WT_BYTES;
static constexpr size_t OFF_GSUM = OFF_HEAT + 262144;
static constexpr size_t OFF_HM = OFF_GSUM + 256;
static constexpr size_t OFF_SC = OFF_HM + 262144;
static constexpr size_t OFF_IDX = OFF_SC + 262144;
static constexpr size_t OFF_FTB = OFF_IDX + 16384;                       // 4096*1024*2
static constexpr size_t OFF_FSB = OFF_FTB + (size_t)4096 * 1024 * 2;     // 4096*512*2
static constexpr size_t OFF_WTT = OFF_FSB + (size_t)4096 * 512 * 2;      // 256*1024*2
static constexpr size_t OFF_WTS = OFF_WTT + (size_t)256 * 1024 * 2;      // 256*512*2
static constexpr size_t OFF_PRT = OFF_WTS + (size_t)256 * 512 * 2;       // 4096*256*4
static constexpr size_t OFF_PRS = OFF_PRT + (size_t)4096 * 256 * 4;
static constexpr size_t OFF_FTN = OFF_PRS + (size_t)4096 * 256 * 4;
static constexpr size_t OFF_FSN = OFF_FTN + (size_t)4096 * 256 * 4;
static constexpr size_t OFF_FSNB = OFF_FSN + (size_t)4096 * 256 * 4;
static constexpr size_t OFF_POS = OFF_FSNB + (size_t)4096 * 256 * 2;
static constexpr size_t OFF_BD = OFF_POS + 16384;
static constexpr size_t OFF_CNT = OFF_BD + 16384;
static constexpr size_t OFF_NBC = OFF_CNT + 64;
static constexpr size_t OFF_RL = OFF_NBC + 64;

extern "C" void kernel_launch(void* const* d_in, const int* in_sizes, int n_in,
                              void* d_out, int out_size, void* d_ws, size_t ws_size,
                              hipStream_t stream) {
  const float* teacher = (const float*)d_in[0];
  const float* student = (const float*)d_in[1];
  const float* w1 = (const float*)d_in[2];
  const float* b1 = (const float*)d_in[3];
  const float* w2 = (const float*)d_in[4];
  const float* b2 = (const float*)d_in[5];
  const float* t_w = (const float*)d_in[6];
  const float* t_b = (const float*)d_in[7];
  const float* t_g = (const float*)d_in[8];
  const float* t_be = (const float*)d_in[9];
  const float* s_w = (const float*)d_in[10];
  const float* s_b = (const float*)d_in[11];
  const float* s_g = (const float*)d_in[12];
  const float* s_be = (const float*)d_in[13];
  float* out = (float*)d_out;

  char* ws = (char*)d_ws;
  unsigned short* tpad = (unsigned short*)(ws + OFF_TPAD);
  unsigned short* wt = (unsigned short*)(ws + OFF_WT);
  float* heat = (float*)(ws + OFF_HEAT);
  float* gsum = (float*)(ws + OFF_GSUM);
  float* hm = (float*)(ws + OFF_HM);
  float* scores = (float*)(ws + OFF_SC);
  int* idx_sel = (int*)(ws + OFF_IDX);
  unsigned short* ftb = (unsigned short*)(ws + OFF_FTB);
  unsigned short* fsb = (unsigned short*)(ws + OFF_FSB);
  unsigned short* wTt = (unsigned short*)(ws + OFF_WTT);
  unsigned short* wTs = (unsigned short*)(ws + OFF_WTS);
  float* projt = (float*)(ws + OFF_PRT);
  float* projs = (float*)(ws + OFF_PRS);
  float* ftn = (float*)(ws + OFF_FTN);
  float* fsn = (float*)(ws + OFF_FSN);
  unsigned short* fsnb = (unsigned short*)(ws + OFF_FSNB);
  float* pos = (float*)(ws + OFF_POS);
  int* bd = (int*)(ws + OFF_BD);
  int* cnt = (int*)(ws + OFF_CNT);
  int* nbc = (int*)(ws + OFF_NBC);
  float* rowloss = (float*)(ws + OFF_RL);

  hipMemsetAsync(ws + OFF_HEAT, 0, 262144 + 256, stream);  // heat + gsum

  k_pad_transpose<<<16384, 256, 0, stream>>>(teacher, tpad);
  k_wprep<<<18432, 256, 0, stream>>>(w1, wt);
  k_wT<<<1024, 256, 0, stream>>>(t_w, wTt, 1024);
  k_wT<<<512, 256, 0, stream>>>(s_w, wTs, 512);
  k_conv<<<2048, 256, 0, stream>>>(tpad, wt, b1, w2, heat);
  k_heat2score<<<16, 256, 0, stream>>>(heat, b2, out + 3, hm, scores);
  k_topk<<<16, 256, 0, stream>>>(scores, idx_sel);
  k_gather_t<<<4096, 256, 0, stream>>>(tpad, idx_sel, ftb);
  k_gather_s<<<256, 256, 0, stream>>>(student, idx_sel, fsb);
  k_proj<<<64, 256, 0, stream>>>(ftb, wTt, 1024, projt);
  k_proj<<<64, 256, 0, stream>>>(fsb, wTs, 512, projs);
  k_ln<<<4096, 256, 0, stream>>>(projt, t_b, t_g, t_be, ftn, (unsigned short*)nullptr);
  k_ln<<<4096, 256, 0, stream>>>(projs, s_b, s_g, s_be, fsn, fsnb);
  k_sal<<<16, 256, 0, stream>>>(hm, idx_sel, bd, cnt, nbc);
  k_pos_gafd<<<4096, 256, 0, stream>>>(fsn, ftn, pos, gsum);
  k_abcd_rows<<<64, 256, 0, stream>>>(fsnb, bd, pos, rowloss);
  k_final<<<1, 256, 0, stream>>>(gsum, rowloss, bd, cnt, nbc, out);
}

// Round 3
// 1346.796 us; speedup vs baseline: 1.7715x; 1.0617x over previous
//
#include <hip/hip_runtime.h>
#include <stdint.h>

// ---------------------------------------------------------------------------
// GAFD_ABCD pipeline on MI355X.  R3: XOR-swizzled LDS in k_conv (kill the
// 2.27e8 bank-conflict cycles), coalesced student gather, coalesced wprep.
// ---------------------------------------------------------------------------

typedef float f32x4 __attribute__((ext_vector_type(4)));
typedef short s16x8 __attribute__((ext_vector_type(8)));

__device__ __forceinline__ unsigned short f2bf(float f) {
  unsigned u = __float_as_uint(f);
  u += 0x7fffu + ((u >> 16) & 1u);   // RNE
  return (unsigned short)(u >> 16);
}
__device__ __forceinline__ float bf2f(unsigned short h) {
  return __uint_as_float((unsigned)h << 16);
}

__device__ __forceinline__ void gld16(const void* g, void* l) {
  __builtin_amdgcn_global_load_lds(
      (const __attribute__((address_space(1))) void*)g,
      (__attribute__((address_space(3))) void*)l, 16, 0, 0);
}

__device__ __forceinline__ float block_sum(float v, float* l4) {
  for (int m = 32; m; m >>= 1) v += __shfl_xor(v, m, 64);
  int wid = threadIdx.x >> 6;
  if ((threadIdx.x & 63) == 0) l4[wid] = v;
  __syncthreads();
  float r = l4[0] + l4[1] + l4[2] + l4[3];
  __syncthreads();
  return r;
}

// --------------------------- K0: pad-transpose + borders -------------------
__global__ void k_pad_transpose(const float* __restrict__ teacher,
                                unsigned short* __restrict__ tpad) {
  __shared__ __align__(16) unsigned short lds[64 * 65];
  int bid = blockIdx.x;
  int cb = bid & 15, y = (bid >> 4) & 63, b = bid >> 10;
  int t = threadIdx.x;
#pragma unroll
  for (int it = 0; it < 16; ++it) {
    int idx = it * 256 + t;
    int cl = idx >> 6, x = idx & 63;
    float v = teacher[(size_t)(b * 1024 + cb * 64 + cl) * 4096 + y * 64 + x];
    lds[cl * 65 + x] = f2bf(v);
  }
  __syncthreads();
  size_t obase = ((size_t)(b * 66 + y + 1) * 66 + 1) * 1024 + cb * 64;
#pragma unroll
  for (int it = 0; it < 16; ++it) {
    int x = it * 4 + (t >> 6);
    int cl = t & 63;
    tpad[obase + (size_t)x * 1024 + cl] = lds[cl * 65 + x];
  }
  if (y == 0) {
    for (int idx = t; idx < 66 * 64; idx += 256) {
      int col = idx >> 6, cl = idx & 63;
      tpad[((size_t)(b * 66) * 66 + col) * 1024 + cb * 64 + cl] = 0;
    }
  }
  if (y == 63) {
    for (int idx = t; idx < 66 * 64; idx += 256) {
      int col = idx >> 6, cl = idx & 63;
      tpad[((size_t)(b * 66 + 65) * 66 + col) * 1024 + cb * 64 + cl] = 0;
    }
  }
  if (t < 128) {
    int col = (t >= 64) ? 65 : 0;
    int cl = t & 63;
    tpad[((size_t)(b * 66 + y + 1) * 66 + col) * 1024 + cb * 64 + cl] = 0;
  }
}

// --------------------------- K0b: conv weight prep (coalesced) -------------
// conv1_w [co=512][ci=1024][3][3] -> wt[tap][kb][co 512][kc 64] bf16
__global__ void k_wprep(const float* __restrict__ w1,
                        unsigned short* __restrict__ wt) {
  __shared__ float wl[9216];
  int co = blockIdx.x, t = threadIdx.x;
  const float* src = w1 + (size_t)co * 9216;
  for (int i = t; i < 9216; i += 256) wl[i] = src[i];
  __syncthreads();
  for (int i = t; i < 9216; i += 256) {
    int tap = i >> 10;            // i = tap*1024 + ci, tap 0..8
    int ci = i - (tap << 10);
    int kb = ci >> 6, kc = ci & 63;
    wt[(size_t)tap * 524288 + (size_t)kb * 32768 + co * 64 + kc] = f2bf(wl[ci * 9 + tap]);
  }
}

// --------------------------- K0c: proj weight transpose --------------------
__global__ void k_wT(const float* __restrict__ w, unsigned short* __restrict__ wT,
                     int K) {
  int e = blockIdx.x * 256 + threadIdx.x;
  int p = e / K, k = e - p * K;
  wT[e] = f2bf(w[(size_t)k * 256 + p]);
}

// --------------------------- K1: conv GEMM (swizzled LDS) ------------------
// LDS rows are 128B (64 bf16); 16B chunk c of row r stored at chunk c^(r&7).
__global__ __launch_bounds__(256) void k_conv(
    const unsigned short* __restrict__ tpad, const unsigned short* __restrict__ wt,
    const float* __restrict__ b1, const float* __restrict__ w2,
    float* __restrict__ heat) {
  __shared__ __align__(16) unsigned short As[128 * 64];
  __shared__ __align__(16) unsigned short Bs[128 * 64];
  int bid = blockIdx.x;
  int nt = bid & 3, mt = bid >> 2;
  int p0 = mt * 128;
  int b = p0 >> 12, y0 = (p0 >> 6) & 63;
  int co0 = nt * 128;
  int t = threadIdx.x, wid = t >> 6, lane = t & 63;
  int wm = wid & 1, wn = wid >> 1;
  int quad = lane >> 4, l15 = lane & 15;
  int sw7 = l15 & 7;  // row-swizzle key for fragment reads

  f32x4 acc[4][4];
  const f32x4 fz = {0.f, 0.f, 0.f, 0.f};
#pragma unroll
  for (int i = 0; i < 4; ++i)
#pragma unroll
    for (int j = 0; j < 4; ++j) acc[i][j] = fz;

  int xj[4], yrj[4];
#pragma unroll
  for (int jj = 0; jj < 4; ++jj) {
    int m = (wid * 4 + jj) * 8 + (lane >> 3);
    xj[jj] = m & 63;
    yrj[jj] = m >> 6;
  }
  // swizzled source chunk: lane covers chunk (lane&7)^(lane>>3) of its row
  int kcol = (((lane & 7) ^ ((lane >> 3) & 7))) * 8;
  int brow = ((lane >> 3) & 7) * 64;  // row-within-8-group offset (shorts)
  const unsigned short* wt_nt = wt + (size_t)co0 * 64;

  for (int tap = 0; tap < 9; ++tap) {
    int ky = tap / 3, kx = tap - ky * 3;
    size_t abase[4];
#pragma unroll
    for (int jj = 0; jj < 4; ++jj) {
      int row = y0 + yrj[jj] + ky;
      int col = xj[jj] + kx;
      abase[jj] = ((size_t)(b * 66 + row) * 66 + col) * 1024 + kcol;
    }
    size_t bbase = (size_t)tap * 16 * 32768;
    for (int kb = 0; kb < 16; ++kb) {
#pragma unroll
      for (int jj = 0; jj < 4; ++jj) {
        gld16(tpad + abase[jj] + kb * 64, (char*)As + (wid * 4 + jj) * 1024);
        gld16(wt_nt + bbase + (size_t)kb * 32768 + (wid * 4 + jj) * 512 + brow + kcol,
              (char*)Bs + (wid * 4 + jj) * 1024);
      }
      __syncthreads();
#pragma unroll
      for (int s = 0; s < 2; ++s) {
        s16x8 af[4], bf[4];
        int chunk = ((s * 4 + quad) ^ sw7) * 8;
#pragma unroll
        for (int i = 0; i < 4; ++i) {
          af[i] = *(const s16x8*)(const void*)(As + (wm * 64 + i * 16 + l15) * 64 + chunk);
          bf[i] = *(const s16x8*)(const void*)(Bs + (wn * 64 + i * 16 + l15) * 64 + chunk);
        }
#pragma unroll
        for (int i = 0; i < 4; ++i)
#pragma unroll
          for (int j = 0; j < 4; ++j)
            acc[i][j] = __builtin_amdgcn_mfma_f32_16x16x32_bf16(af[i], bf[j], acc[i][j], 0, 0, 0);
      }
      __syncthreads();
    }
  }

  float w2v[4], b1v[4];
#pragma unroll
  for (int j = 0; j < 4; ++j) {
    int co = co0 + wn * 64 + j * 16 + l15;
    w2v[j] = w2[co];
    b1v[j] = b1[co];
  }
#pragma unroll
  for (int i = 0; i < 4; ++i) {
#pragma unroll
    for (int r = 0; r < 4; ++r) {
      float part = 0.f;
#pragma unroll
      for (int j = 0; j < 4; ++j) {
        float v = acc[i][j][r] + b1v[j];
        v = fmaxf(v, 0.f);
        part += v * w2v[j];
      }
#pragma unroll
      for (int msk = 1; msk < 16; msk <<= 1) part += __shfl_xor(part, msk, 64);
      if (l15 == 0) {
        int m = wm * 64 + i * 16 + quad * 4 + r;
        atomicAdd(&heat[p0 + m], part);
      }
    }
  }
}

// --------------------------- threefry (JAX partitionable) ------------------
__device__ __forceinline__ unsigned rotl32(unsigned x, int d) {
  return (x << d) | (x >> (32 - d));
}
__device__ unsigned threefry_bits(unsigned lo) {
  const unsigned k0 = 0u, k1 = 42u;
  const unsigned k2 = 0x1BD11BDAu ^ k0 ^ k1;
  unsigned x0 = 0u + k0, x1 = lo + k1;
#define TF_R4(a, bq, c, d)                                \
  x0 += x1; x1 = rotl32(x1, a); x1 ^= x0;                 \
  x0 += x1; x1 = rotl32(x1, bq); x1 ^= x0;                \
  x0 += x1; x1 = rotl32(x1, c); x1 ^= x0;                 \
  x0 += x1; x1 = rotl32(x1, d); x1 ^= x0;
  TF_R4(13, 15, 26, 6)  x0 += k1; x1 += k2 + 1u;
  TF_R4(17, 29, 16, 24) x0 += k2; x1 += k0 + 2u;
  TF_R4(13, 15, 26, 6)  x0 += k0; x1 += k1 + 3u;
  TF_R4(17, 29, 16, 24) x0 += k1; x1 += k2 + 4u;
  TF_R4(13, 15, 26, 6)  x0 += k2; x1 += k0 + 5u;
#undef TF_R4
  return x0 ^ x1;
}

// --------------------------- K2: softplus / prob / scores ------------------
__global__ void k_heat2score(const float* __restrict__ heat, const float* __restrict__ b2p,
                             float* __restrict__ out_hm, float* __restrict__ hm,
                             float* __restrict__ scores) {
  __shared__ float l4[4];
  int b = blockIdx.x, t = threadIdx.x;
  float b2 = b2p[0];
  float hv[16];
  float lsum = 0.f;
#pragma unroll
  for (int j = 0; j < 16; ++j) {
    int e = j * 256 + t;
    float x = heat[b * 4096 + e] + b2;
    float sp = fmaxf(x, 0.f) + log1pf(expf(-fabsf(x)));
    hv[j] = sp;
    lsum += sp;
  }
  float S = block_sum(lsum, l4);
  float denom = S + 1e-6f;
#pragma unroll
  for (int j = 0; j < 16; ++j) {
    int e = j * 256 + t;
    float sp = hv[j];
    out_hm[b * 4096 + e] = sp;
    hm[b * 4096 + e] = sp;
    float lp = logf(sp / denom + 1e-12f);
    unsigned bits = threefry_bits((unsigned)(b * 4096 + e));
    float u01 = __uint_as_float((bits >> 9) | 0x3f800000u) - 1.0f;
    float u = fmaxf(1e-8f, u01 * (1.0f - 1e-8f) + 1e-8f);
    float gum = -logf(-logf(u));
    scores[b * 4096 + e] = lp + gum;
  }
}

// --------------------------- K3: exact top-256 via radix select ------------
__global__ void k_topk(const float* __restrict__ scores, int* __restrict__ idx_sel) {
  __shared__ unsigned keys[4096];
  __shared__ unsigned hist[256];
  __shared__ unsigned suf[256];
  __shared__ unsigned sel[2];
  __shared__ int wpos;
  int b = blockIdx.x, t = threadIdx.x;
#pragma unroll
  for (int j = 0; j < 16; ++j) {
    unsigned u = __float_as_uint(scores[b * 4096 + j * 256 + t]);
    u = (u >> 31) ? ~u : (u | 0x80000000u);
    keys[j * 256 + t] = u;
  }
  if (t == 0) wpos = 0;
  unsigned prefix = 0, hmask = 0, r = 256;
  for (int pass = 0; pass < 4; ++pass) {
    int shift = 24 - 8 * pass;
    hist[t] = 0;
    __syncthreads();
#pragma unroll
    for (int j = 0; j < 16; ++j) {
      unsigned u = keys[j * 256 + t];
      if ((u & hmask) == prefix) atomicAdd(&hist[(u >> shift) & 255u], 1u);
    }
    __syncthreads();
    suf[t] = hist[t];
    __syncthreads();
    for (int off = 1; off < 256; off <<= 1) {
      unsigned v = (t + off < 256) ? suf[t + off] : 0u;
      __syncthreads();
      suf[t] += v;
      __syncthreads();
    }
    unsigned above = (t < 255) ? suf[t + 1] : 0u;
    if (suf[t] >= r && above < r) {
      sel[0] = (unsigned)t;
      sel[1] = above;
    }
    __syncthreads();
    prefix |= sel[0] << shift;
    hmask |= 0xFFu << shift;
    r -= sel[1];
    __syncthreads();
  }
#pragma unroll
  for (int j = 0; j < 16; ++j) {
    int e = j * 256 + t;
    if (keys[e] > prefix) {
      int s = atomicAdd(&wpos, 1);
      idx_sel[b * 256 + s] = e;
    }
  }
  __syncthreads();
#pragma unroll
  for (int j = 0; j < 16; ++j) {
    int e = j * 256 + t;
    if (keys[e] == prefix) {
      int s = atomicAdd(&wpos, 1);
      if (s < 256) idx_sel[b * 256 + s] = e;
    }
  }
}

// --------------------------- K4a: teacher gather from tpad -----------------
__global__ void k_gather_t(const unsigned short* __restrict__ tpad,
                           const int* __restrict__ idx_sel,
                           unsigned short* __restrict__ ftb) {
  int bn = blockIdx.x;
  int b = bn >> 8;
  int idx = idx_sel[bn];
  int px = idx & 63, py = idx >> 6;
  const unsigned short* base = tpad + ((size_t)(b * 66 + py) * 66 + px) * 1024;
  for (int c = threadIdx.x; c < 1024; c += 256) {
    float v = bf2f(base[c]) + bf2f(base[c + 1024]) +
              bf2f(base[c + 66 * 1024]) + bf2f(base[c + 67 * 1024]);
    ftb[(size_t)bn * 1024 + c] = f2bf(0.25f * v);
  }
}

// --------------------------- K4b: student gather (plane in LDS) ------------
// Block = (b, channel). Coalesced plane load; gather from LDS; write
// channel-major fsbT[(b*512+c)*256 + n] (contiguous per block).
__global__ void k_gather_s(const float* __restrict__ student,
                           const int* __restrict__ idx_sel,
                           unsigned short* __restrict__ fsbT) {
  __shared__ float plane[4096];
  int blk = blockIdx.x;
  int b = blk >> 9, c = blk & 511;
  int t = threadIdx.x;
  const float4* g4 = (const float4*)(student + ((size_t)b * 512 + c) * 4096);
  float4* p4 = (float4*)plane;
  for (int i = t; i < 1024; i += 256) p4[i] = g4[i];
  __syncthreads();
  int idx = idx_sel[b * 256 + t];
  int px = idx & 63, py = idx >> 6;
  float v = 0.f;
  if (py > 0) {
    if (px > 0) v += plane[(py - 1) * 64 + px - 1];
    v += plane[(py - 1) * 64 + px];
  }
  if (px > 0) v += plane[py * 64 + px - 1];
  v += plane[py * 64 + px];
  fsbT[((size_t)b * 512 + c) * 256 + t] = f2bf(0.25f * v);
}

// --------------------------- K4c: fsbT -> fsb transpose --------------------
// fsbT [b][512][256] -> fsb [b*256+n][512], 64x64 LDS tiles both coalesced.
__global__ void k_fsb_tr(const unsigned short* __restrict__ fsbT,
                         unsigned short* __restrict__ fsb) {
  __shared__ unsigned short tile[64][65];
  int blk = blockIdx.x;
  int b = blk >> 5, ct = (blk >> 2) & 7, nt = blk & 3;
  int t = threadIdx.x;
#pragma unroll
  for (int it = 0; it < 16; ++it) {
    int e = it * 256 + t;
    int cl = e >> 6, n = e & 63;
    tile[cl][n] = fsbT[((size_t)(b * 512 + ct * 64 + cl)) * 256 + nt * 64 + n];
  }
  __syncthreads();
#pragma unroll
  for (int it = 0; it < 16; ++it) {
    int e = it * 256 + t;
    int n = e >> 6, cl = e & 63;
    fsb[((size_t)(b * 256 + nt * 64 + n)) * 512 + ct * 64 + cl] = tile[cl][n];
  }
}

// --------------------------- K5: projection GEMM (MFMA) --------------------
__global__ __launch_bounds__(256) void k_proj(
    const unsigned short* __restrict__ A, const unsigned short* __restrict__ Wt,
    int K, float* __restrict__ outp) {
  __shared__ __align__(16) unsigned short As[128 * 64];
  __shared__ __align__(16) unsigned short Bs[128 * 64];
  int bid = blockIdx.x;
  int nt = bid & 1, mt = bid >> 1;
  int m0 = mt * 128, n0 = nt * 128;
  int t = threadIdx.x, wid = t >> 6, lane = t & 63;
  int wm = wid & 1, wn = wid >> 1;
  int quad = lane >> 4, l15 = lane & 15;

  f32x4 acc[4][4];
  const f32x4 fz = {0.f, 0.f, 0.f, 0.f};
#pragma unroll
  for (int i = 0; i < 4; ++i)
#pragma unroll
    for (int j = 0; j < 4; ++j) acc[i][j] = fz;

  int row4[4];
#pragma unroll
  for (int jj = 0; jj < 4; ++jj) row4[jj] = (wid * 4 + jj) * 8 + (lane >> 3);
  int kcol = (lane & 7) * 8;

  int nkb = K >> 6;
  for (int kb = 0; kb < nkb; ++kb) {
#pragma unroll
    for (int jj = 0; jj < 4; ++jj) {
      gld16(A + (size_t)(m0 + row4[jj]) * K + kb * 64 + kcol,
            (char*)As + (wid * 4 + jj) * 1024);
      gld16(Wt + (size_t)(n0 + row4[jj]) * K + kb * 64 + kcol,
            (char*)Bs + (wid * 4 + jj) * 1024);
    }
    __syncthreads();
#pragma unroll
    for (int s = 0; s < 2; ++s) {
      s16x8 af[4], bf[4];
#pragma unroll
      for (int i = 0; i < 4; ++i) {
        af[i] = *(const s16x8*)(const void*)(As + (wm * 64 + i * 16 + l15) * 64 + s * 32 + quad * 8);
        bf[i] = *(const s16x8*)(const void*)(Bs + (wn * 64 + i * 16 + l15) * 64 + s * 32 + quad * 8);
      }
#pragma unroll
      for (int i = 0; i < 4; ++i)
#pragma unroll
        for (int j = 0; j < 4; ++j)
          acc[i][j] = __builtin_amdgcn_mfma_f32_16x16x32_bf16(af[i], bf[j], acc[i][j], 0, 0, 0);
    }
    __syncthreads();
  }
#pragma unroll
  for (int i = 0; i < 4; ++i)
#pragma unroll
    for (int j = 0; j < 4; ++j)
#pragma unroll
      for (int r = 0; r < 4; ++r) {
        int m = m0 + wm * 64 + i * 16 + quad * 4 + r;
        int p = n0 + wn * 64 + j * 16 + l15;
        outp[(size_t)m * 256 + p] = acc[i][j][r];
      }
}

// --------------------------- K5b: bias + LN + l2norm -----------------------
__global__ void k_ln(const float* __restrict__ projp, const float* __restrict__ bias,
                     const float* __restrict__ g, const float* __restrict__ beta,
                     float* __restrict__ outf, unsigned short* __restrict__ outb) {
  __shared__ float l4[4];
  int row = blockIdx.x, t = threadIdx.x;
  float x = projp[(size_t)row * 256 + t] + bias[t];
  float s1 = block_sum(x, l4);
  float mu = s1 * (1.f / 256.f);
  float d = x - mu;
  float s2 = block_sum(d * d, l4);
  float rstd = rsqrtf(s2 * (1.f / 256.f) + 1e-5f);
  float xn = d * rstd * g[t] + beta[t];
  float ss = block_sum(xn * xn, l4);
  float o = xn / fmaxf(sqrtf(ss), 1e-12f);
  outf[(size_t)row * 256 + t] = o;
  if (outb) outb[(size_t)row * 256 + t] = f2bf(o);
}

// --------------------------- K6: saliency / bd ----------------------------
__global__ void k_sal(const float* __restrict__ hm, const int* __restrict__ idx_sel,
                      int* __restrict__ bd, int* __restrict__ cnt, int* __restrict__ nbc) {
  __shared__ float l4[4];
  int b = blockIdx.x, t = threadIdx.x;
  int idx = idx_sel[b * 256 + t];
  int px = idx & 63, py = idx >> 6;
  const float* hb = hm + b * 4096;
  float v = 0.f;
  if (py > 0) {
    if (px > 0) v += hb[(py - 1) * 64 + px - 1];
    v += hb[(py - 1) * 64 + px];
  }
  if (px > 0) v += hb[py * 64 + px - 1];
  v += hb[py * 64 + px];
  float sal = 0.25f * v;
  float mx = sal;
  for (int m = 32; m; m >>= 1) mx = fmaxf(mx, __shfl_xor(mx, m, 64));
  if ((t & 63) == 0) l4[t >> 6] = mx;
  __syncthreads();
  mx = fmaxf(fmaxf(l4[0], l4[1]), fmaxf(l4[2], l4[3]));
  __syncthreads();
  int bdv = sal > 0.6f * mx ? 1 : 0;
  bd[b * 256 + t] = bdv;
  float c = block_sum((float)bdv, l4);
  if (t == 0) {
    cnt[b] = (int)c;
    nbc[b] = 256 - (int)c;
  }
}

// --------------------------- K6b: pos + gafd -------------------------------
__global__ void k_pos_gafd(const float* __restrict__ fsn, const float* __restrict__ ftn,
                           float* __restrict__ pos, float* __restrict__ gsum) {
  __shared__ float l4[4];
  int row = blockIdx.x, t = threadIdx.x;
  float a = fsn[(size_t)row * 256 + t];
  float bt = ftn[(size_t)row * 256 + t];
  float sdot = block_sum(a * bt, l4);
  if (t == 0) pos[row] = sdot * 10.f;  // / TAU
  float d = a - bt;
  float ssq = block_sum(d * d, l4);
  if (t == 0) atomicAdd(gsum, ssq);
}

// --------------------------- K7: neg matrix + masked LSE -------------------
__global__ __launch_bounds__(256) void k_abcd_rows(
    const unsigned short* __restrict__ fsnb, const int* __restrict__ bd,
    const float* __restrict__ pos, float* __restrict__ rowloss) {
  __shared__ __align__(16) unsigned short Ab[64 * 64];
  __shared__ __align__(16) unsigned short Bb[256 * 64];
  __shared__ float mrg[64][4][2];
  int b = blockIdx.x >> 2, nb = blockIdx.x & 3;
  int n0 = nb * 64;
  int t = threadIdx.x, w = t >> 6, lane = t & 63, quad = lane >> 4, l15 = lane & 15;
  f32x4 acc[4][4];
  const f32x4 fz = {0.f, 0.f, 0.f, 0.f};
#pragma unroll
  for (int i = 0; i < 4; ++i)
#pragma unroll
    for (int j = 0; j < 4; ++j) acc[i][j] = fz;
  const unsigned short* fb = fsnb + (size_t)b * 256 * 256;

  for (int kc = 0; kc < 4; ++kc) {
    {
      int r = t >> 2, cc = (t & 3) * 16;
      const uint4* s = (const uint4*)(const void*)(fb + (size_t)(n0 + r) * 256 + kc * 64 + cc);
      *(uint4*)(void*)(Ab + r * 64 + cc) = s[0];
      *(uint4*)(void*)(Ab + r * 64 + cc + 8) = s[1];
    }
#pragma unroll
    for (int it = 0; it < 4; ++it) {
      int m = it * 64 + (t >> 2), cc = (t & 3) * 16;
      const uint4* s = (const uint4*)(const void*)(fb + (size_t)m * 256 + kc * 64 + cc);
      *(uint4*)(void*)(Bb + m * 64 + cc) = s[0];
      *(uint4*)(void*)(Bb + m * 64 + cc + 8) = s[1];
    }
    __syncthreads();
#pragma unroll
    for (int s = 0; s < 2; ++s) {
      s16x8 af[4], bf[4];
#pragma unroll
      for (int i = 0; i < 4; ++i) {
        af[i] = *(const s16x8*)(const void*)(Ab + (i * 16 + l15) * 64 + s * 32 + quad * 8);
        bf[i] = *(const s16x8*)(const void*)(Bb + (w * 64 + i * 16 + l15) * 64 + s * 32 + quad * 8);
      }
#pragma unroll
      for (int i = 0; i < 4; ++i)
#pragma unroll
        for (int j = 0; j < 4; ++j)
          acc[i][j] = __builtin_amdgcn_mfma_f32_16x16x32_bf16(af[i], bf[j], acc[i][j], 0, 0, 0);
    }
    __syncthreads();
  }

  int nbmask[4];
#pragma unroll
  for (int j = 0; j < 4; ++j) nbmask[j] = bd[b * 256 + w * 64 + j * 16 + l15];
#pragma unroll
  for (int i = 0; i < 4; ++i) {
#pragma unroll
    for (int r = 0; r < 4; ++r) {
      float mxv = -1e30f, se = 0.f;
#pragma unroll
      for (int j = 0; j < 4; ++j) {
        float v = nbmask[j] ? -1e30f : (acc[i][j][r] / 0.1f);
        if (v > mxv) {
          se = se * expf(mxv - v) + 1.f;
          mxv = v;
        } else {
          se += expf(v - mxv);
        }
      }
#pragma unroll
      for (int msk = 1; msk < 16; msk <<= 1) {
        float omx = __shfl_xor(mxv, msk, 64);
        float ose = __shfl_xor(se, msk, 64);
        float nm = fmaxf(mxv, omx);
        se = se * expf(mxv - nm) + ose * expf(omx - nm);
        mxv = nm;
      }
      if (l15 == 0) {
        mrg[i * 16 + quad * 4 + r][w][0] = mxv;
        mrg[i * 16 + quad * 4 + r][w][1] = se;
      }
    }
  }
  __syncthreads();
  if (t < 64) {
    float MX = -1e30f, SE = 0.f;
    for (int ww = 0; ww < 4; ++ww) {
      float omx = mrg[t][ww][0], ose = mrg[t][ww][1];
      float nm = fmaxf(MX, omx);
      SE = SE * expf(MX - nm) + ose * expf(omx - nm);
      MX = nm;
    }
    float p = pos[b * 256 + n0 + t];
    float nm = fmaxf(MX, p);
    float se2 = SE * expf(MX - nm) + expf(p - nm);
    rowloss[b * 256 + n0 + t] = nm + logf(se2) - p;
  }
}

// --------------------------- K8: final scalars -----------------------------
__global__ void k_final(const float* __restrict__ gsum, const float* __restrict__ rowloss,
                        const int* __restrict__ bd, const int* __restrict__ cnt,
                        const int* __restrict__ nbc, float* __restrict__ out) {
  __shared__ float l4[4];
  int t = threadIdx.x;
  float abcd_acc = 0.f, vnum = 0.f;
  for (int b = 0; b < 16; ++b) {
    float c = bd[b * 256 + t] ? rowloss[b * 256 + t] : 0.f;
    float s = block_sum(c, l4);
    if (t == 0) {
      float cb = (float)cnt[b];
      float per = s / fmaxf(cb, 1.f);
      if (cnt[b] > 0 && nbc[b] > 0) {
        abcd_acc += per;
        vnum += 1.f;
      }
    }
  }
  if (t == 0) {
    float gafd = gsum[0] / 1048576.f;
    float abcd = vnum > 0.f ? abcd_acc / fmaxf(vnum, 1.f) : 0.f;
    out[0] = gafd + 0.5f * abcd;
    out[1] = gafd;
    out[2] = abcd;
  }
}

// --------------------------- workspace layout ------------------------------
static constexpr size_t OFF_TPAD = 0;
static constexpr size_t TPAD_BYTES = (size_t)16 * 66 * 66 * 1024 * 2;
static constexpr size_t OFF_WT = OFF_TPAD + TPAD_BYTES;
static constexpr size_t WT_BYTES = (size_t)9 * 16 * 512 * 64 * 2;
static constexpr size_t OFF_HEAT = OFF_WT + WT_BYTES;
static constexpr size_t OFF_GSUM = OFF_HEAT + 262144;
static constexpr size_t OFF_HM = OFF_GSUM + 256;
static constexpr size_t OFF_SC = OFF_HM + 262144;
static constexpr size_t OFF_IDX = OFF_SC + 262144;
static constexpr size_t OFF_FTB = OFF_IDX + 16384;
static constexpr size_t OFF_FSB = OFF_FTB + (size_t)4096 * 1024 * 2;
static constexpr size_t OFF_FSBT = OFF_FSB + (size_t)4096 * 512 * 2;
static constexpr size_t OFF_WTT = OFF_FSBT + (size_t)4096 * 512 * 2;
static constexpr size_t OFF_WTS = OFF_WTT + (size_t)256 * 1024 * 2;
static constexpr size_t OFF_PRT = OFF_WTS + (size_t)256 * 512 * 2;
static constexpr size_t OFF_PRS = OFF_PRT + (size_t)4096 * 256 * 4;
static constexpr size_t OFF_FTN = OFF_PRS + (size_t)4096 * 256 * 4;
static constexpr size_t OFF_FSN = OFF_FTN + (size_t)4096 * 256 * 4;
static constexpr size_t OFF_FSNB = OFF_FSN + (size_t)4096 * 256 * 4;
static constexpr size_t OFF_POS = OFF_FSNB + (size_t)4096 * 256 * 2;
static constexpr size_t OFF_BD = OFF_POS + 16384;
static constexpr size_t OFF_CNT = OFF_BD + 16384;
static constexpr size_t OFF_NBC = OFF_CNT + 64;
static constexpr size_t OFF_RL = OFF_NBC + 64;

extern "C" void kernel_launch(void* const* d_in, const int* in_sizes, int n_in,
                              void* d_out, int out_size, void* d_ws, size_t ws_size,
                              hipStream_t stream) {
  const float* teacher = (const float*)d_in[0];
  const float* student = (const float*)d_in[1];
  const float* w1 = (const float*)d_in[2];
  const float* b1 = (const float*)d_in[3];
  const float* w2 = (const float*)d_in[4];
  const float* b2 = (const float*)d_in[5];
  const float* t_w = (const float*)d_in[6];
  const float* t_b = (const float*)d_in[7];
  const float* t_g = (const float*)d_in[8];
  const float* t_be = (const float*)d_in[9];
  const float* s_w = (const float*)d_in[10];
  const float* s_b = (const float*)d_in[11];
  const float* s_g = (const float*)d_in[12];
  const float* s_be = (const float*)d_in[13];
  float* out = (float*)d_out;

  char* ws = (char*)d_ws;
  unsigned short* tpad = (unsigned short*)(ws + OFF_TPAD);
  unsigned short* wt = (unsigned short*)(ws + OFF_WT);
  float* heat = (float*)(ws + OFF_HEAT);
  float* gsum = (float*)(ws + OFF_GSUM);
  float* hm = (float*)(ws + OFF_HM);
  float* scores = (float*)(ws + OFF_SC);
  int* idx_sel = (int*)(ws + OFF_IDX);
  unsigned short* ftb = (unsigned short*)(ws + OFF_FTB);
  unsigned short* fsb = (unsigned short*)(ws + OFF_FSB);
  unsigned short* fsbT = (unsigned short*)(ws + OFF_FSBT);
  unsigned short* wTt = (unsigned short*)(ws + OFF_WTT);
  unsigned short* wTs = (unsigned short*)(ws + OFF_WTS);
  float* projt = (float*)(ws + OFF_PRT);
  float* projs = (float*)(ws + OFF_PRS);
  float* ftn = (float*)(ws + OFF_FTN);
  float* fsn = (float*)(ws + OFF_FSN);
  unsigned short* fsnb = (unsigned short*)(ws + OFF_FSNB);
  float* pos = (float*)(ws + OFF_POS);
  int* bd = (int*)(ws + OFF_BD);
  int* cnt = (int*)(ws + OFF_CNT);
  int* nbc = (int*)(ws + OFF_NBC);
  float* rowloss = (float*)(ws + OFF_RL);

  hipMemsetAsync(ws + OFF_HEAT, 0, 262144 + 256, stream);  // heat + gsum

  k_pad_transpose<<<16384, 256, 0, stream>>>(teacher, tpad);
  k_wprep<<<512, 256, 0, stream>>>(w1, wt);
  k_wT<<<1024, 256, 0, stream>>>(t_w, wTt, 1024);
  k_wT<<<512, 256, 0, stream>>>(s_w, wTs, 512);
  k_conv<<<2048, 256, 0, stream>>>(tpad, wt, b1, w2, heat);
  k_heat2score<<<16, 256, 0, stream>>>(heat, b2, out + 3, hm, scores);
  k_topk<<<16, 256, 0, stream>>>(scores, idx_sel);
  k_gather_t<<<4096, 256, 0, stream>>>(tpad, idx_sel, ftb);
  k_gather_s<<<8192, 256, 0, stream>>>(student, idx_sel, fsbT);
  k_fsb_tr<<<512, 256, 0, stream>>>(fsbT, fsb);
  k_proj<<<64, 256, 0, stream>>>(ftb, wTt, 1024, projt);
  k_proj<<<64, 256, 0, stream>>>(fsb, wTs, 512, projs);
  k_ln<<<4096, 256, 0, stream>>>(projt, t_b, t_g, t_be, ftn, (unsigned short*)nullptr);
  k_ln<<<4096, 256, 0, stream>>>(projs, s_b, s_g, s_be, fsn, fsnb);
  k_sal<<<16, 256, 0, stream>>>(hm, idx_sel, bd, cnt, nbc);
  k_pos_gafd<<<4096, 256, 0, stream>>>(fsn, ftn, pos, gsum);
  k_abcd_rows<<<64, 256, 0, stream>>>(fsnb, bd, pos, rowloss);
  k_final<<<1, 256, 0, stream>>>(gsum, rowloss, bd, cnt, nbc, out);
}